// Round 6
// baseline (807.786 us; speedup 1.0000x reference)
//
#include <hip/hip_runtime.h>
#include <hip/hip_bf16.h>
#include <stdint.h>

// CrossAttention on MI355X (gfx950), bf16 MFMA pipeline.
// R6: (1) flash grid 512->1024: 128-thr/2-wave blocks (wave keeps 64 q-rows),
//   LDS 18KB -> 8 blocks/CU = 16 waves/CU (R5 was grid-capped at 2 blocks/CU,
//   20% occupancy). (2) V pre-packed by transpose_v into PV-B-operand layout
//   vP[g][hb][l16][quad][8] -> flash stages V with linear gl_lds16 and reads
//   frags as b128 (2-way conflicts only). (3) GEMM XCD swizzle: xcd=bid&7 owns
//   8 row-panels x all col-blocks -> A+B L2-resident per XCD; per-iter barrier
//   drain waits on L2 (~200cyc) not HBM (~900cyc) re-fetches.

typedef __bf16 bf16_t;
typedef __bf16 bf16x8 __attribute__((ext_vector_type(8)));
typedef __bf16 bf16x4 __attribute__((ext_vector_type(4)));
typedef short  s16x4  __attribute__((ext_vector_type(4)));
typedef float  f32x4  __attribute__((ext_vector_type(4)));

#define BB 4
#define NN 2048
#define KC 2048
#define DD 1024
#define NH 16
#define HD 64
// 0.125 (=HEAD_DIM^-0.5) * log2(e): softmax done in exp2 domain
#define QSCALE 0.18033688011112042f
#define CLIP2  14.426950408889634f

__device__ __forceinline__ f32x4 mfma_16x16x32(bf16x8 a, bf16x8 b, f32x4 c) {
  return __builtin_amdgcn_mfma_f32_16x16x32_bf16(a, b, c, 0, 0, 0);
}

// async global->LDS, 16B per lane; LDS dest is wave-uniform base + lane*16.
__device__ __forceinline__ void gl_lds16(const bf16_t* g, bf16_t* l) {
  __builtin_amdgcn_global_load_lds(
      (const __attribute__((address_space(1))) void*)g,
      (__attribute__((address_space(3))) void*)l, 16, 0, 0);
}

// ---------------- elementwise f32 -> bf16 ----------------
__global__ __launch_bounds__(256) void cvt_f32_bf16(const float* __restrict__ in,
                                                    bf16_t* __restrict__ out, int n4) {
  int i = blockIdx.x * 256 + threadIdx.x;
  if (i >= n4) return;
  float4 v = ((const float4*)in)[i];
  bf16x4 o = {(bf16_t)v.x, (bf16_t)v.y, (bf16_t)v.z, (bf16_t)v.w};
  ((bf16x4*)out)[i] = o;
}

// ---------------- RMSNorm rows of 1024, f32 in -> bf16 out ----------------
__global__ __launch_bounds__(256) void rmsnorm_rows(const float* __restrict__ in,
                                                    bf16_t* __restrict__ out) {
  int row = blockIdx.x, tid = threadIdx.x;
  float4 v = ((const float4*)(in + (size_t)row * DD))[tid];
  float ss = v.x * v.x + v.y * v.y + v.z * v.z + v.w * v.w;
#pragma unroll
  for (int m = 1; m < 64; m <<= 1) ss += __shfl_xor(ss, m);
  __shared__ float wsum[4];
  if ((tid & 63) == 0) wsum[tid >> 6] = ss;
  __syncthreads();
  float total = wsum[0] + wsum[1] + wsum[2] + wsum[3];
  float scale = rsqrtf(total * (1.0f / (float)DD) + 1e-6f);
  bf16x4 o = {(bf16_t)(v.x * scale), (bf16_t)(v.y * scale),
              (bf16_t)(v.z * scale), (bf16_t)(v.w * scale)};
  ((bf16x4*)(out + (size_t)row * DD))[tid] = o;
}

// ---------------- weight transpose: W (R x C) f32 -> WT (C x R) bf16 ----------------
__global__ __launch_bounds__(256) void transpose_w(const float* __restrict__ W,
                                                   bf16_t* __restrict__ WT, int R, int C) {
  __shared__ float tile[32][33];
  int tx = threadIdx.x & 31, ty = threadIdx.x >> 5;
  int r0 = blockIdx.y * 32, c0 = blockIdx.x * 32;
#pragma unroll
  for (int i = 0; i < 4; i++) tile[ty + 8 * i][tx] = W[(size_t)(r0 + ty + 8 * i) * C + c0 + tx];
  __syncthreads();
#pragma unroll
  for (int i = 0; i < 4; i++)
    WT[(size_t)(c0 + ty + 8 * i) * R + r0 + tx] = (bf16_t)tile[tx][ty + 8 * i];
}

// ---------------- GEMM: C(MxN) = (A(MxK) @ Bt(NxK)^T + bias) * alpha ----------------
// 1D grid = gx*64 blocks (M=8192 fixed -> 64 row-panels). XCD swizzle: xcd=bid&7
// owns row-panels [xcd*8, xcd*8+8) x all gx col-blocks -> A-panel (2MB) + B
// (2-4MB) stay in that XCD's L2 across the whole K-loop.
template <int OUT_F32>
__global__ __launch_bounds__(256, 2) void gemm_bt(const bf16_t* __restrict__ A,
                                                  const bf16_t* __restrict__ Bt,
                                                  const float* __restrict__ bias,
                                                  void* __restrict__ Cout, int M, int N,
                                                  int Kd, float alpha, int gxlog) {
  __shared__ bf16_t As[128 * 32];
  __shared__ bf16_t Bs[128 * 32];
  int tid = threadIdx.x;
  int w = tid >> 6, lane = tid & 63;
  int quad = lane >> 4, l16 = lane & 15;
  int bid = blockIdx.x;
  int xcd = bid & 7, idx = bid >> 3;
  int row0 = (xcd * 8 + (idx >> gxlog)) * 128;
  int col0 = (idx & ((1 << gxlog) - 1)) * 128;
  int wm = (w >> 1) * 64, wn = (w & 1) * 64;

  f32x4 acc[4][4];
#pragma unroll
  for (int i = 0; i < 4; i++)
#pragma unroll
    for (int j = 0; j < 4; j++) acc[i][j] = (f32x4){0.f, 0.f, 0.f, 0.f};

  for (int kk = 0; kk < Kd; kk += 32) {
#pragma unroll
    for (int call = 0; call < 2; call++) {
      int c = w * 128 + call * 64 + lane;
      gl_lds16(&A[(size_t)(row0 + (c >> 2)) * Kd + kk + (c & 3) * 8],
               &As[(w * 128 + call * 64) * 8]);
      gl_lds16(&Bt[(size_t)(col0 + (c >> 2)) * Kd + kk + (c & 3) * 8],
               &Bs[(w * 128 + call * 64) * 8]);
    }
    __syncthreads();
    bf16x8 af[4], bfr[4];
#pragma unroll
    for (int mi = 0; mi < 4; mi++)
      af[mi] = *(const bf16x8*)&As[(wm + mi * 16 + l16) * 32 + quad * 8];
#pragma unroll
    for (int ni = 0; ni < 4; ni++)
      bfr[ni] = *(const bf16x8*)&Bs[(wn + ni * 16 + l16) * 32 + quad * 8];
#pragma unroll
    for (int mi = 0; mi < 4; mi++)
#pragma unroll
      for (int ni = 0; ni < 4; ni++) acc[mi][ni] = mfma_16x16x32(af[mi], bfr[ni], acc[mi][ni]);
    __syncthreads();
  }

#pragma unroll
  for (int ni = 0; ni < 4; ni++) {
    int col = col0 + wn + ni * 16 + l16;
    float bv = bias[col];
#pragma unroll
    for (int mi = 0; mi < 4; mi++) {
#pragma unroll
      for (int r = 0; r < 4; r++) {
        int row = row0 + wm + mi * 16 + quad * 4 + r;
        float v = (acc[mi][ni][r] + bv) * alpha;
        if (OUT_F32)
          ((float*)Cout)[(size_t)row * N + col] = v;
        else
          ((bf16_t*)Cout)[(size_t)row * N + col] = (bf16_t)v;
      }
    }
  }
}

// ---------------- V repack: kvbuf -> vP in PV-B-operand layout ----------------
// vP[(bh,t)][g][hb][l16][quad][8j]; elem = V[key = kc0 + g*32 + quad*4 + (j&3)
// + (j>>2)*16][hd = hb*16 + l16]. Flash reads b128 at l16*64B+quad*16B (2-way
// conflicts only) and stages with pure-linear gl_lds16.
__global__ __launch_bounds__(256) void transpose_v(const bf16_t* __restrict__ kvbuf,
                                                   bf16_t* __restrict__ vP) {
  __shared__ bf16_t tile[64][72];
  int bh = blockIdx.y;
  int b = bh >> 4, h = bh & 15;
  int t = blockIdx.x;
  int kc0 = t * 64;
  int tid = threadIdx.x;
#pragma unroll
  for (int i = 0; i < 2; i++) {
    int ch = tid + i * 256;
    int key = ch >> 3, cc = ch & 7;
    *(bf16x8*)&tile[key][cc * 8] =
        *(const bf16x8*)&kvbuf[((size_t)b * KC + kc0 + key) * (2 * DD) + DD + h * HD + cc * 8];
  }
  __syncthreads();
#pragma unroll
  for (int i = 0; i < 2; i++) {
    int c = tid + i * 256;  // chunk index [0,512)
    int g = c >> 8, hb = (c >> 6) & 3, l16 = (c >> 2) & 15, quad = c & 3;
    bf16x8 v;
#pragma unroll
    for (int j = 0; j < 8; j++)
      v[j] = tile[g * 32 + quad * 4 + (j & 3) + (j >> 2) * 16][hb * 16 + l16];
    *(bf16x8*)&vP[((size_t)bh * 32 + t) * 4096 + c * 8] = v;
  }
}

// ---------------- flash attention: query-split, qi=4, 2-wave blocks ----------------
// 1024 blocks x 128 thr; wave w owns q-rows [n0+w*64, +64). Per 64-key tile:
// stage K (64x64, +pad) manually + vP (8KB) via linear gl_lds16; 64 K=32 MFMAs
// per wave (32 S^T + 32 PV via C-frag concat). 18KB LDS -> 8 blocks/CU.
__global__ __launch_bounds__(128, 4) void flash_attn(const bf16_t* __restrict__ qbuf,
                                                     const bf16_t* __restrict__ kvbuf,
                                                     const bf16_t* __restrict__ vP,
                                                     bf16_t* __restrict__ attn_out) {
  __shared__ bf16_t Ks[64][72];
  __shared__ bf16_t Vp[4096];  // [g][hb][l16][quad][8]
  __shared__ float rsinvS[2][64];

  int tid = threadIdx.x, w = tid >> 6, lane = tid & 63;
  int quad = lane >> 4, l16 = lane & 15;
  // 1024 blocks; xcd = bid&7 owns 8 whole (b,h): K+V 4MB = one XCD L2.
  int bid = blockIdx.x;
  int xcd = bid & 7, slot = bid >> 3;  // slot in [0,128)
  int bh = xcd * 8 + (slot >> 4);
  int qt = slot & 15;
  int b = bh >> 4, h = bh & 15;
  int n0 = qt * 128 + w * 64;  // wave-private 64 q-rows

  const bf16_t* kbase = kvbuf + (size_t)b * KC * (2 * DD) + (size_t)h * HD;
  const bf16_t* vpb = vP + (size_t)bh * 32 * 4096;

  // Q-frags: B-operand of S^T. B[k=d=quad*8+j][n=query=qi*16+l16].
  bf16x8 qf[4][2];
#pragma unroll
  for (int qi = 0; qi < 4; qi++)
#pragma unroll
    for (int dc = 0; dc < 2; dc++)
      qf[qi][dc] = *(const bf16x8*)&qbuf[((size_t)b * NN + n0 + qi * 16 + l16) * DD + h * HD +
                                         dc * 32 + quad * 8];

  f32x4 o[4][4];  // [qi][hb]; C: row=quad*4+r = q-within-16, col=l16 = hd-within-16
#pragma unroll
  for (int qi = 0; qi < 4; qi++)
#pragma unroll
    for (int hb = 0; hb < 4; hb++) o[qi][hb] = (f32x4){0.f, 0.f, 0.f, 0.f};
  float rs[4] = {0.f, 0.f, 0.f, 0.f};

  for (int t = 0; t < KC / 64; t++) {
    int kc0 = t * 64;
    __syncthreads();  // prev iter's frag reads done
#pragma unroll
    for (int i = 0; i < 4; i++) {  // stage K tile 64x64 (padded rows)
      int idx = tid + i * 128;
      int r = idx >> 3, c = idx & 7;
      *(bf16x8*)&Ks[r][c * 8] = *(const bf16x8*)&kbase[(size_t)(kc0 + r) * (2 * DD) + c * 8];
    }
#pragma unroll
    for (int i = 0; i < 4; i++) {  // stage vP tile 8KB, pure-linear DMA
      int j = w * 4 + i;
      gl_lds16(&vpb[(size_t)t * 4096 + j * 512 + lane * 8], &Vp[j * 512]);
    }
    __syncthreads();  // drains vmcnt (gl_lds16) + lgkm

    // K frags: A[m=key=l16][k=d=quad*8+j] per 16-key subtile, per d-half.
    bf16x8 kf[4][2];
#pragma unroll
    for (int ki = 0; ki < 4; ki++)
#pragma unroll
      for (int dc = 0; dc < 2; dc++)
        kf[ki][dc] = *(const bf16x8*)&Ks[ki * 16 + l16][dc * 32 + quad * 8];
    // V frags (b128): slot(quad,j) -> key g*32 + quad*4 + (j&3) + (j>>2)*16.
    bf16x8 vb[2][4];
#pragma unroll
    for (int g = 0; g < 2; g++)
#pragma unroll
      for (int hb = 0; hb < 4; hb++)
        vb[g][hb] = *(const bf16x8*)&Vp[(g * 4 + hb) * 512 + l16 * 32 + quad * 8];

#pragma unroll
    for (int qi = 0; qi < 4; qi++) {
#pragma unroll
      for (int g = 0; g < 2; g++) {
        union { bf16x8 v8; bf16x4 h[2]; } pf;
#pragma unroll
        for (int sub = 0; sub < 2; sub++) {
          f32x4 s = (f32x4){0.f, 0.f, 0.f, 0.f};
          s = mfma_16x16x32(kf[g * 2 + sub][0], qf[qi][0], s);
          s = mfma_16x16x32(kf[g * 2 + sub][1], qf[qi][1], s);
          bf16x4 pb;
#pragma unroll
          for (int r = 0; r < 4; r++) {
            float pv = __builtin_amdgcn_exp2f(__builtin_amdgcn_fmed3f(s[r], -CLIP2, CLIP2));
            rs[qi] += pv;
            pb[r] = (bf16_t)pv;
          }
          pf.h[sub] = pb;
        }
#pragma unroll
        for (int hb = 0; hb < 4; hb++)
          o[qi][hb] = mfma_16x16x32(pf.v8, vb[g][hb], o[qi][hb]);
      }
    }
  }

  // full row-sums (sum quads; intra-wave LDS broadcast, no barrier needed)
#pragma unroll
  for (int qi = 0; qi < 4; qi++) {
    float v = rs[qi];
    v += __shfl_xor(v, 16);
    v += __shfl_xor(v, 32);
    if (quad == 0) rsinvS[w][qi * 16 + l16] = 1.0f / v;
  }
#pragma unroll
  for (int qi = 0; qi < 4; qi++) {
    f32x4 ri = *(const f32x4*)&rsinvS[w][qi * 16 + quad * 4];
#pragma unroll
    for (int hb = 0; hb < 4; hb++) {
#pragma unroll
      for (int r = 0; r < 4; r++) {
        int row = n0 + qi * 16 + quad * 4 + r;
        int col = h * HD + hb * 16 + l16;
        attn_out[((size_t)b * NN + row) * DD + col] = (bf16_t)(o[qi][hb][r] * ri[r]);
      }
    }
  }
}

__global__ void write_mean(float* out) { out[0] = 1.0f / 2048.0f; }

// ---------------- launch ----------------
extern "C" void kernel_launch(void* const* d_in, const int* in_sizes, int n_in, void* d_out,
                              int out_size, void* d_ws, size_t ws_size, hipStream_t stream) {
  const float* x      = (const float*)d_in[0];
  const float* ctx    = (const float*)d_in[1];
  const float* q_w    = (const float*)d_in[2];
  const float* q_b    = (const float*)d_in[3];
  const float* kv_w   = (const float*)d_in[4];
  const float* kv_b   = (const float*)d_in[5];
  const float* proj_w = (const float*)d_in[6];
  const float* proj_b = (const float*)d_in[7];
  float* out = (float*)d_out;
  char* ws = (char*)d_ws;

  bf16_t* xb    = (bf16_t*)(ws + 0);          // 16 MB, dead after q GEMM
  bf16_t* ctxn  = (bf16_t*)(ws + 16777216);   // 16 MB, dead after kv GEMM
  bf16_t* qwT   = (bf16_t*)(ws + 33554432);   // 2 MB
  bf16_t* kvwT  = (bf16_t*)(ws + 35651584);   // 4 MB
  bf16_t* pwT   = (bf16_t*)(ws + 39845888);   // 2 MB
  bf16_t* qbuf  = (bf16_t*)(ws + 41943040);   // 16 MB
  bf16_t* kvbuf = (bf16_t*)(ws + 58720256);   // 32 MB
  bf16_t* vP       = ctxn;                    // alias: written after ctxn consumed (16 MB)
  bf16_t* attn_out = xb;                      // alias: written after xb consumed

  cvt_f32_bf16<<<8192, 256, 0, stream>>>(x, xb, (BB * NN * DD) / 4);
  rmsnorm_rows<<<BB * KC, 256, 0, stream>>>(ctx, ctxn);
  transpose_w<<<dim3(32, 32), 256, 0, stream>>>(q_w, qwT, DD, DD);
  transpose_w<<<dim3(64, 32), 256, 0, stream>>>(kv_w, kvwT, DD, 2 * DD);
  transpose_w<<<dim3(32, 32), 256, 0, stream>>>(proj_w, pwT, DD, DD);
  // q = (x @ q_w + q_b) * (SCALE*log2e)  -> softmax uses exp2
  gemm_bt<0><<<512, 256, 0, stream>>>(xb, qwT, q_b, qbuf, BB * NN, DD, DD, QSCALE, 3);
  gemm_bt<0><<<1024, 256, 0, stream>>>(ctxn, kvwT, kv_b, kvbuf, BB * KC, 2 * DD, DD, 1.0f, 4);
  transpose_v<<<dim3(KC / 64, BB * NH), 256, 0, stream>>>(kvbuf, vP);
  flash_attn<<<1024, 128, 0, stream>>>(qbuf, kvbuf, vP, attn_out);
  gemm_bt<1><<<512, 256, 0, stream>>>(attn_out, pwT, proj_b, out, BB * NN, DD, DD, 1.0f, 3);
  write_mean<<<1, 1, 0, stream>>>(out + (size_t)out_size - 1);
}

// Round 7
// 335.835 us; speedup vs baseline: 2.4053x; 2.4053x over previous
//
#include <hip/hip_runtime.h>
#include <hip/hip_bf16.h>
#include <stdint.h>

// CrossAttention on MI355X (gfx950), bf16 MFMA pipeline.
// R7: flash = R5 structure (verified 91us) + occupancy fixed the RIGHT way:
//   128-thr/2-wave blocks, grid 1024, launch_bounds(128,2) -> 256-reg budget
//   (R4/R6 lesson: this kernel needs the full 256; (128,4) spilled 2.6GB).
//   4 blocks/CU = 4 independent barrier groups (R5 had 2, grid-capped).
//   K and V both pre-packed into MFMA-fragment order BY THE KV-GEMM EPILOGUE
//   (separable row/col index parts): flash stages via pure-linear gl_lds16
//   DMA and reads conflict-free b128 frags; transpose_v deleted (-32MB).

typedef __bf16 bf16_t;
typedef __bf16 bf16x8 __attribute__((ext_vector_type(8)));
typedef __bf16 bf16x4 __attribute__((ext_vector_type(4)));
typedef float  f32x4  __attribute__((ext_vector_type(4)));

#define BB 4
#define NN 2048
#define KC 2048
#define DD 1024
#define NH 16
#define HD 64
// 0.125 (=HEAD_DIM^-0.5) * log2(e): softmax done in exp2 domain
#define QSCALE 0.18033688011112042f
#define CLIP2  14.426950408889634f

__device__ __forceinline__ f32x4 mfma_16x16x32(bf16x8 a, bf16x8 b, f32x4 c) {
  return __builtin_amdgcn_mfma_f32_16x16x32_bf16(a, b, c, 0, 0, 0);
}

// async global->LDS, 16B per lane; LDS dest is wave-uniform base + lane*16.
__device__ __forceinline__ void gl_lds16(const bf16_t* g, bf16_t* l) {
  __builtin_amdgcn_global_load_lds(
      (const __attribute__((address_space(1))) void*)g,
      (__attribute__((address_space(3))) void*)l, 16, 0, 0);
}

// ---------------- elementwise f32 -> bf16 ----------------
__global__ __launch_bounds__(256) void cvt_f32_bf16(const float* __restrict__ in,
                                                    bf16_t* __restrict__ out, int n4) {
  int i = blockIdx.x * 256 + threadIdx.x;
  if (i >= n4) return;
  float4 v = ((const float4*)in)[i];
  bf16x4 o = {(bf16_t)v.x, (bf16_t)v.y, (bf16_t)v.z, (bf16_t)v.w};
  ((bf16x4*)out)[i] = o;
}

// ---------------- RMSNorm rows of 1024, f32 in -> bf16 out ----------------
__global__ __launch_bounds__(256) void rmsnorm_rows(const float* __restrict__ in,
                                                    bf16_t* __restrict__ out) {
  int row = blockIdx.x, tid = threadIdx.x;
  float4 v = ((const float4*)(in + (size_t)row * DD))[tid];
  float ss = v.x * v.x + v.y * v.y + v.z * v.z + v.w * v.w;
#pragma unroll
  for (int m = 1; m < 64; m <<= 1) ss += __shfl_xor(ss, m);
  __shared__ float wsum[4];
  if ((tid & 63) == 0) wsum[tid >> 6] = ss;
  __syncthreads();
  float total = wsum[0] + wsum[1] + wsum[2] + wsum[3];
  float scale = rsqrtf(total * (1.0f / (float)DD) + 1e-6f);
  bf16x4 o = {(bf16_t)(v.x * scale), (bf16_t)(v.y * scale),
              (bf16_t)(v.z * scale), (bf16_t)(v.w * scale)};
  ((bf16x4*)(out + (size_t)row * DD))[tid] = o;
}

// ---------------- weight transpose: W (R x C) f32 -> WT (C x R) bf16 ----------------
__global__ __launch_bounds__(256) void transpose_w(const float* __restrict__ W,
                                                   bf16_t* __restrict__ WT, int R, int C) {
  __shared__ float tile[32][33];
  int tx = threadIdx.x & 31, ty = threadIdx.x >> 5;
  int r0 = blockIdx.y * 32, c0 = blockIdx.x * 32;
#pragma unroll
  for (int i = 0; i < 4; i++) tile[ty + 8 * i][tx] = W[(size_t)(r0 + ty + 8 * i) * C + c0 + tx];
  __syncthreads();
#pragma unroll
  for (int i = 0; i < 4; i++)
    WT[(size_t)(c0 + ty + 8 * i) * R + r0 + tx] = (bf16_t)tile[tx][ty + 8 * i];
}

// ---------------- GEMM: C(MxN) = (A(MxK) @ Bt(NxK)^T + bias) * alpha ----------------
// MODE 0: bf16 Cout. MODE 1: f32 Cout. MODE 2: kv-pack epilogue (K cols ->
// kP fragment layout, V cols -> vP fragment layout; col0 block is uniformly
// K or V since the 1024 boundary is 128-aligned).
// 1D grid, XCD swizzle: xcd=bid&7 owns row-panels [xcd*8,+8) x all col-blocks.
template <int MODE>
__global__ __launch_bounds__(256, 2) void gemm_bt(const bf16_t* __restrict__ A,
                                                  const bf16_t* __restrict__ Bt,
                                                  const float* __restrict__ bias,
                                                  void* __restrict__ Cout,
                                                  bf16_t* __restrict__ kP,
                                                  bf16_t* __restrict__ vP, int M, int N,
                                                  int Kd, float alpha, int gxlog) {
  __shared__ bf16_t As[128 * 32];
  __shared__ bf16_t Bs[128 * 32];
  int tid = threadIdx.x;
  int w = tid >> 6, lane = tid & 63;
  int quad = lane >> 4, l16 = lane & 15;
  int bid = blockIdx.x;
  int xcd = bid & 7, idx = bid >> 3;
  int row0 = (xcd * 8 + (idx >> gxlog)) * 128;
  int col0 = (idx & ((1 << gxlog) - 1)) * 128;
  int wm = (w >> 1) * 64, wn = (w & 1) * 64;

  f32x4 acc[4][4];
#pragma unroll
  for (int i = 0; i < 4; i++)
#pragma unroll
    for (int j = 0; j < 4; j++) acc[i][j] = (f32x4){0.f, 0.f, 0.f, 0.f};

  for (int kk = 0; kk < Kd; kk += 32) {
#pragma unroll
    for (int call = 0; call < 2; call++) {
      int c = w * 128 + call * 64 + lane;
      gl_lds16(&A[(size_t)(row0 + (c >> 2)) * Kd + kk + (c & 3) * 8],
               &As[(w * 128 + call * 64) * 8]);
      gl_lds16(&Bt[(size_t)(col0 + (c >> 2)) * Kd + kk + (c & 3) * 8],
               &Bs[(w * 128 + call * 64) * 8]);
    }
    __syncthreads();
    bf16x8 af[4], bfr[4];
#pragma unroll
    for (int mi = 0; mi < 4; mi++)
      af[mi] = *(const bf16x8*)&As[(wm + mi * 16 + l16) * 32 + quad * 8];
#pragma unroll
    for (int ni = 0; ni < 4; ni++)
      bfr[ni] = *(const bf16x8*)&Bs[(wn + ni * 16 + l16) * 32 + quad * 8];
#pragma unroll
    for (int mi = 0; mi < 4; mi++)
#pragma unroll
      for (int ni = 0; ni < 4; ni++) acc[mi][ni] = mfma_16x16x32(af[mi], bfr[ni], acc[mi][ni]);
    __syncthreads();
  }

  if (MODE == 2) {
    bool isK = (col0 < 1024);
    int cpart[4];
    float bv[4];
#pragma unroll
    for (int ni = 0; ni < 4; ni++) {
      int col = col0 + wn + ni * 16 + l16;
      bv[ni] = bias[col];
      int ch = isK ? col : (col - 1024);
      int h = ch >> 6, hd = ch & 63;
      if (isK)
        cpart[ni] = h * 131072 + (hd >> 5) * 512 + ((hd >> 3) & 3) * 8 + (hd & 7);
      else
        cpart[ni] = h * 131072 + (hd >> 4) * 512 + (hd & 15) * 32;
    }
#pragma unroll
    for (int mi = 0; mi < 4; mi++) {
#pragma unroll
      for (int r = 0; r < 4; r++) {
        int row = row0 + wm + mi * 16 + quad * 4 + r;
        int bb = row >> 11, kc = row & 2047;
        int t = kc >> 6, key = kc & 63;
        int rpart;
        if (isK) {
          rpart = bb * 2097152 + t * 4096 + (key >> 4) * 1024 + (key & 15) * 32;
        } else {
          int g = key >> 5, k2 = key & 31;
          rpart = bb * 2097152 + t * 4096 + g * 2048 + ((k2 >> 2) & 3) * 8 +
                  (((k2 >> 4) << 2) | (k2 & 3));
        }
        bf16_t* dst = isK ? kP : vP;
#pragma unroll
        for (int ni = 0; ni < 4; ni++)
          dst[(size_t)rpart + cpart[ni]] = (bf16_t)((acc[mi][ni][r] + bv[ni]) * alpha);
      }
    }
    return;
  }

#pragma unroll
  for (int ni = 0; ni < 4; ni++) {
    int col = col0 + wn + ni * 16 + l16;
    float bv = bias[col];
#pragma unroll
    for (int mi = 0; mi < 4; mi++) {
#pragma unroll
      for (int r = 0; r < 4; r++) {
        int row = row0 + wm + mi * 16 + quad * 4 + r;
        float v = (acc[mi][ni][r] + bv) * alpha;
        if (MODE == 1)
          ((float*)Cout)[(size_t)row * N + col] = v;
        else
          ((bf16_t*)Cout)[(size_t)row * N + col] = (bf16_t)v;
      }
    }
  }
}

// ---------------- flash attention: query-split, qi=4, fragment-packed K/V ----------------
// 1024 blocks x 128 thr (2 waves); wave owns 64 q-rows, full key loop.
// Per 64-key tile t: stage kP/vP tiles (8KB each, contiguous) via linear
// gl_lds16 DMA; read conflict-free b128 frags; 64 K=32 MFMAs per wave
// (32 S^T + 32 PV via C-frag concat, k-label agreement).
// kP sub-tile (ki,dc): [l16=key%16][quad][j] -> A[m=l16][k=quad*8+j].
// vP sub-tile (g,hb):  [l16=hd%16][quad][j] -> B[k-slot(quad,j)][n=hd].
__global__ __launch_bounds__(128, 2) void flash_attn(const bf16_t* __restrict__ qbuf,
                                                     const bf16_t* __restrict__ kP,
                                                     const bf16_t* __restrict__ vP,
                                                     bf16_t* __restrict__ attn_out) {
  __shared__ bf16_t Kp[4096];
  __shared__ bf16_t Vp[4096];
  __shared__ float rsinvS[2][64];

  int tid = threadIdx.x, w = tid >> 6, lane = tid & 63;
  int quad = lane >> 4, l16 = lane & 15;
  // 1024 blocks; xcd = bid&7 owns 8 whole (b,h): K+V 4MB = one XCD L2.
  int bid = blockIdx.x;
  int xcd = bid & 7, slot = bid >> 3;  // slot in [0,128)
  int bh = xcd * 8 + (slot >> 4);
  int qt = slot & 15;
  int b = bh >> 4, h = bh & 15;
  int n0 = qt * 128 + w * 64;  // wave-private 64 q-rows

  const bf16_t* kpb = kP + (size_t)bh * 32 * 4096;
  const bf16_t* vpb = vP + (size_t)bh * 32 * 4096;

  // Q-frags: B-operand of S^T. B[k=d=quad*8+j][n=query=qi*16+l16].
  bf16x8 qf[4][2];
#pragma unroll
  for (int qi = 0; qi < 4; qi++)
#pragma unroll
    for (int dc = 0; dc < 2; dc++)
      qf[qi][dc] = *(const bf16x8*)&qbuf[((size_t)b * NN + n0 + qi * 16 + l16) * DD + h * HD +
                                         dc * 32 + quad * 8];

  f32x4 o[4][4];  // [qi][hb]; C: row=quad*4+r = q-within-16, col=l16 = hd-within-16
#pragma unroll
  for (int qi = 0; qi < 4; qi++)
#pragma unroll
    for (int hb = 0; hb < 4; hb++) o[qi][hb] = (f32x4){0.f, 0.f, 0.f, 0.f};
  float rs[4] = {0.f, 0.f, 0.f, 0.f};

  for (int t = 0; t < KC / 64; t++) {
    __syncthreads();  // prev iter's frag reads done
#pragma unroll
    for (int i = 0; i < 4; i++) {  // each wave stages half of K and half of V
      int j = w * 4 + i;
      gl_lds16(&kpb[(size_t)t * 4096 + j * 512 + lane * 8], &Kp[j * 512]);
      gl_lds16(&vpb[(size_t)t * 4096 + j * 512 + lane * 8], &Vp[j * 512]);
    }
    __syncthreads();  // drains vmcnt (gl_lds16 DMA)

    // K frags: A[m=key=l16][k=d=quad*8+j] per (ki,dc); conflict-free b128.
    bf16x8 kf[4][2];
#pragma unroll
    for (int ki = 0; ki < 4; ki++)
#pragma unroll
      for (int dc = 0; dc < 2; dc++)
        kf[ki][dc] = *(const bf16x8*)&Kp[(ki * 2 + dc) * 512 + (l16 * 4 + quad) * 8];
    // V frags: B[k-slot(quad,j) -> key g*32+quad*4+(j&3)+(j>>2)*16][n=hd].
    bf16x8 vb[2][4];
#pragma unroll
    for (int g = 0; g < 2; g++)
#pragma unroll
      for (int hb = 0; hb < 4; hb++)
        vb[g][hb] = *(const bf16x8*)&Vp[(g * 4 + hb) * 512 + (l16 * 4 + quad) * 8];

#pragma unroll
    for (int qi = 0; qi < 4; qi++) {
#pragma unroll
      for (int g = 0; g < 2; g++) {
        union { bf16x8 v8; bf16x4 h[2]; } pf;
#pragma unroll
        for (int sub = 0; sub < 2; sub++) {
          f32x4 s = (f32x4){0.f, 0.f, 0.f, 0.f};
          s = mfma_16x16x32(kf[g * 2 + sub][0], qf[qi][0], s);
          s = mfma_16x16x32(kf[g * 2 + sub][1], qf[qi][1], s);
          bf16x4 pb;
#pragma unroll
          for (int r = 0; r < 4; r++) {
            float pv = __builtin_amdgcn_exp2f(__builtin_amdgcn_fmed3f(s[r], -CLIP2, CLIP2));
            rs[qi] += pv;
            pb[r] = (bf16_t)pv;
          }
          pf.h[sub] = pb;
        }
#pragma unroll
        for (int hb = 0; hb < 4; hb++)
          o[qi][hb] = mfma_16x16x32(pf.v8, vb[g][hb], o[qi][hb]);
      }
    }
  }

  // full row-sums (sum quads; per-wave LDS broadcast, no barrier needed)
#pragma unroll
  for (int qi = 0; qi < 4; qi++) {
    float v = rs[qi];
    v += __shfl_xor(v, 16);
    v += __shfl_xor(v, 32);
    if (quad == 0) rsinvS[w][qi * 16 + l16] = 1.0f / v;
  }
#pragma unroll
  for (int qi = 0; qi < 4; qi++) {
    f32x4 ri = *(const f32x4*)&rsinvS[w][qi * 16 + quad * 4];
#pragma unroll
    for (int hb = 0; hb < 4; hb++) {
#pragma unroll
      for (int r = 0; r < 4; r++) {
        int row = n0 + qi * 16 + quad * 4 + r;
        int col = h * HD + hb * 16 + l16;
        attn_out[((size_t)b * NN + row) * DD + col] = (bf16_t)(o[qi][hb][r] * ri[r]);
      }
    }
  }
}

__global__ void write_mean(float* out) { out[0] = 1.0f / 2048.0f; }

// ---------------- launch ----------------
extern "C" void kernel_launch(void* const* d_in, const int* in_sizes, int n_in, void* d_out,
                              int out_size, void* d_ws, size_t ws_size, hipStream_t stream) {
  const float* x      = (const float*)d_in[0];
  const float* ctx    = (const float*)d_in[1];
  const float* q_w    = (const float*)d_in[2];
  const float* q_b    = (const float*)d_in[3];
  const float* kv_w   = (const float*)d_in[4];
  const float* kv_b   = (const float*)d_in[5];
  const float* proj_w = (const float*)d_in[6];
  const float* proj_b = (const float*)d_in[7];
  float* out = (float*)d_out;
  char* ws = (char*)d_ws;

  bf16_t* xb    = (bf16_t*)(ws + 0);          // 16 MB, dead after q GEMM
  bf16_t* ctxn  = (bf16_t*)(ws + 16777216);   // 16 MB, dead after kv GEMM
  bf16_t* qwT   = (bf16_t*)(ws + 33554432);   // 2 MB
  bf16_t* kvwT  = (bf16_t*)(ws + 35651584);   // 4 MB
  bf16_t* pwT   = (bf16_t*)(ws + 39845888);   // 2 MB
  bf16_t* qbuf  = (bf16_t*)(ws + 41943040);   // 16 MB
  bf16_t* kP    = (bf16_t*)(ws + 58720256);   // 16 MB, fragment-packed K
  bf16_t* vP    = (bf16_t*)(ws + 75497472);   // 16 MB, fragment-packed V
  bf16_t* attn_out = xb;                      // alias: written after xb consumed

  cvt_f32_bf16<<<8192, 256, 0, stream>>>(x, xb, (BB * NN * DD) / 4);
  rmsnorm_rows<<<BB * KC, 256, 0, stream>>>(ctx, ctxn);
  transpose_w<<<dim3(32, 32), 256, 0, stream>>>(q_w, qwT, DD, DD);
  transpose_w<<<dim3(64, 32), 256, 0, stream>>>(kv_w, kvwT, DD, 2 * DD);
  transpose_w<<<dim3(32, 32), 256, 0, stream>>>(proj_w, pwT, DD, DD);
  // q = (x @ q_w + q_b) * (SCALE*log2e)  -> softmax uses exp2
  gemm_bt<0><<<512, 256, 0, stream>>>(xb, qwT, q_b, qbuf, nullptr, nullptr,
                                      BB * NN, DD, DD, QSCALE, 3);
  // kv GEMM with fragment-packing epilogue (writes kP + vP directly)
  gemm_bt<2><<<1024, 256, 0, stream>>>(ctxn, kvwT, kv_b, nullptr, kP, vP,
                                       BB * KC, 2 * DD, DD, 1.0f, 4);
  flash_attn<<<1024, 128, 0, stream>>>(qbuf, kP, vP, attn_out);
  gemm_bt<1><<<512, 256, 0, stream>>>(attn_out, pwT, proj_b, out, nullptr, nullptr,
                                      BB * NN, DD, DD, 1.0f, 3);
  write_mean<<<1, 1, 0, stream>>>(out + (size_t)out_size - 1);
}